// Round 15
// baseline (454.052 us; speedup 1.0000x reference)
//
#include <hip/hip_runtime.h>
#include <stdint.h>

#define N_PTS 4096
#define B_SZ 8
#define D_DIM 64
#define KNN 20
#define NROWS (B_SZ * N_PTS)   // 32768
#define H1C 32
#define H2C 64
#define BN_EPS 1e-3f
#define NSLICE 2
#define SLICE_C (N_PTS / NSLICE)   // 2048 candidates per block
#define NSUB (SLICE_C / 16)        // 128 subtiles per block

typedef __attribute__((ext_vector_type(8))) short bf16x8;
typedef __attribute__((ext_vector_type(4))) float f32x4;
typedef unsigned long long ull;

__device__ __forceinline__ ushort f2bf(float f) {
    uint32_t u = __float_as_uint(f);
    uint32_t r = (u + 0x7fffu + ((u >> 16) & 1u)) >> 16;
    return (ushort)r;
}
__device__ __forceinline__ float bf2f(ushort h) {
    return __uint_as_float(((uint32_t)h) << 16);
}

// sorted ascending top-20 insert (cold paths: end-merge, knn_merge)
__device__ __forceinline__ void ins20(ull (&k)[KNN], ull cur) {
#pragma unroll
    for (int p = KNN - 1; p >= 1; --p) {
        bool c = cur < k[p - 1];
        ull t = (k[p] < cur) ? k[p] : cur;
        k[p] = c ? k[p - 1] : t;
    }
    k[0] = (k[0] < cur) ? k[0] : cur;
}

// compare-exchange ascending
__device__ __forceinline__ void ce_asc(ull& a, ull& b) {
    bool c = b < a;
    ull lo = c ? b : a;
    ull hi = c ? a : b;
    a = lo;
    b = hi;
}

// Merge batch e[8] (empty slots = ~0ull = +inf) into sorted-asc k[20], keep smallest 20.
// Fixed bitonic network; exact (split property). See r14 notes.
__device__ __forceinline__ void merge8(ull (&k)[KNN], ull (&e)[8]) {
    ce_asc(e[0], e[1]); ce_asc(e[2], e[3]); ce_asc(e[4], e[5]); ce_asc(e[6], e[7]);
    ce_asc(e[0], e[2]); ce_asc(e[1], e[3]); ce_asc(e[4], e[6]); ce_asc(e[5], e[7]);
    ce_asc(e[1], e[2]); ce_asc(e[5], e[6]);
    ce_asc(e[0], e[4]); ce_asc(e[1], e[5]); ce_asc(e[2], e[6]); ce_asc(e[3], e[7]);
    ce_asc(e[2], e[4]); ce_asc(e[3], e[5]);
    ce_asc(e[1], e[2]); ce_asc(e[3], e[4]); ce_asc(e[5], e[6]);
    ull u[12];
    u[0] = k[16]; u[1] = k[17]; u[2] = k[18]; u[3] = k[19];
#pragma unroll
    for (int j = 0; j < 8; ++j) {
        ull a = k[8 + j], b = e[7 - j];
        bool c = b < a;
        k[8 + j] = c ? b : a;
        ull hi = c ? a : b;
        if (j < 4) u[8 + j] = hi;
        else       u[j]     = hi;
    }
#pragma unroll
    for (int j = 0; j < 8; ++j) ce_asc(k[j], k[j + 8]);
#pragma unroll
    for (int j = 0; j < 4; ++j) { ce_asc(k[j], k[j + 4]); ce_asc(k[8 + j], k[12 + j]); }
#pragma unroll
    for (int j = 0; j < 2; ++j) {
        ce_asc(k[j], k[j + 2]);       ce_asc(k[4 + j], k[6 + j]);
        ce_asc(k[8 + j], k[10 + j]);  ce_asc(k[12 + j], k[14 + j]);
    }
#pragma unroll
    for (int j = 0; j < 16; j += 2) ce_asc(k[j], k[j + 1]);
#pragma unroll
    for (int j = 0; j < 4; ++j) ce_asc(u[j], u[j + 8]);
#pragma unroll
    for (int j = 0; j < 4; ++j) ce_asc(u[j], u[j + 4]);
    ce_asc(u[0], u[2]); ce_asc(u[1], u[3]);
    ce_asc(u[0], u[1]); ce_asc(u[2], u[3]);
    k[16] = u[0]; k[17] = u[1]; k[18] = u[2]; k[19] = u[3];
}

// ---------------------------------------------------- K0: split fp32 -> bf16 hi/lo + sq
__global__ void prep_kernel(const float* __restrict__ x, ushort* __restrict__ xh,
                            ushort* __restrict__ xl, float* __restrict__ sq) {
    int row = blockIdx.x * blockDim.x + threadIdx.x;
    if (row >= NROWS) return;
    const float4* xr = (const float4*)(x + (size_t)row * D_DIM);
    ushort4* ho = (ushort4*)(xh + (size_t)row * D_DIM);
    ushort4* lo = (ushort4*)(xl + (size_t)row * D_DIM);
    float acc = 0.f;
#pragma unroll
    for (int q = 0; q < 16; ++q) {
        float4 v = xr[q];
        acc = fmaf(v.x, v.x, acc);
        acc = fmaf(v.y, v.y, acc);
        acc = fmaf(v.z, v.z, acc);
        acc = fmaf(v.w, v.w, acc);
        ushort4 h, l;
        h.x = f2bf(v.x); l.x = f2bf(v.x - bf2f(h.x));
        h.y = f2bf(v.y); l.y = f2bf(v.y - bf2f(h.y));
        h.z = f2bf(v.z); l.z = f2bf(v.z - bf2f(h.z));
        h.w = f2bf(v.w); l.w = f2bf(v.w - bf2f(h.w));
        ho[q] = h; lo[q] = l;
    }
    sq[row] = acc;
}

// ---------------------------------------------------- K1: MFMA dist + pipelined scan
// r14 structure (exact u64 keys, 8-deep reg buffer, drain __any(cnt>=5), merge8 network,
// dual-bound thr, XCD-aligned batches). THIS ROUND: software-pipelined candidate loads —
// subtile i+1's 5 vectors prefetch into regs while subtile i computes (grid caps occupancy
// at 4 waves/SIMD, so the +~24 VGPR are free below 128). Last-iter prefetch re-reads the
// current subtile (never consumed). Selected sets bit-identical.
// launch_bounds min-waves MUST stay 4 — 6 forces VGPR cap -> scratch spill (r7: 2.3 GB).
__global__ __launch_bounds__(256, 4) void dist_topk(
    const ushort* __restrict__ xh, const ushort* __restrict__ xl,
    const float* __restrict__ sq, ull* __restrict__ part) {
    int tid = threadIdx.x;
    int lane = tid & 63;
    int w = tid >> 6;
    int b = blockIdx.x & 7;           // batch = XCD (round-robin alignment, r13)
    int blk = blockIdx.x >> 3;        // row-group within batch (0..63)
    int slice = blockIdx.y;
    const ushort* xhb = xh + (size_t)b * N_PTS * D_DIM;
    const ushort* xlb = xl + (size_t)b * N_PTS * D_DIM;
    const float* sqb = sq + (size_t)b * N_PTS;

    int qr0 = blk * 64 + w * 16;          // wave's query-row base (within batch)
    int fr = lane & 15;                   // query row within 16 (C col)
    int fg = lane >> 4;                   // k-group / candidate sub-row group

    // B fragments = query rows, resident all kernel
    bf16x8 q_h[2], q_l[2];
    {
        const ushort* ph = xhb + (size_t)(qr0 + fr) * D_DIM + fg * 8;
        const ushort* pl = xlb + (size_t)(qr0 + fr) * D_DIM + fg * 8;
        q_h[0] = *(const bf16x8*)(ph);
        q_h[1] = *(const bf16x8*)(ph + 32);
        q_l[0] = *(const bf16x8*)(pl);
        q_l[1] = *(const bf16x8*)(pl + 32);
    }
    float sqi = sqb[qr0 + fr];

    ull k20[KNN];
#pragma unroll
    for (int p = 0; p < KNN; ++p) k20[p] = ~0ull;
    ull e[8];
#pragma unroll
    for (int i = 0; i < 8; ++i) e[i] = ~0ull;
    int cnt = 0;
    unsigned thr = 0xFFFFFFFFu;

    int cbase = slice * SLICE_C;
    const ushort* pah = xhb + (size_t)(cbase + fr) * D_DIM + fg * 8;
    const ushort* pal = xlb + (size_t)(cbase + fr) * D_DIM + fg * 8;
    const float* psq = sqb + cbase + fg * 4;

    // prefetch subtile 0
    bf16x8 n_h0 = *(const bf16x8*)(pah);
    bf16x8 n_h1 = *(const bf16x8*)(pah + 32);
    bf16x8 n_l0 = *(const bf16x8*)(pal);
    bf16x8 n_l1 = *(const bf16x8*)(pal + 32);
    float4 n_sq = *(const float4*)(psq);

#pragma unroll 4
    for (int i = 0; i < NSUB; ++i) {
        bf16x8 a_h0 = n_h0, a_h1 = n_h1, a_l0 = n_l0, a_l1 = n_l1;
        float4 sqj = n_sq;
        // prefetch subtile i+1 (last iter: re-read current, never consumed)
        int adv = (i == NSUB - 1) ? 0 : 16 * D_DIM;
        int advq = (i == NSUB - 1) ? 0 : 16;
        pah += adv; pal += adv; psq += advq;
        n_h0 = *(const bf16x8*)(pah);
        n_h1 = *(const bf16x8*)(pah + 32);
        n_l0 = *(const bf16x8*)(pal);
        n_l1 = *(const bf16x8*)(pal + 32);
        n_sq = *(const float4*)(psq);

        int cc = cbase + i * 16;
        f32x4 accA = {0.f, 0.f, 0.f, 0.f};   // hh chain
        f32x4 accB = {0.f, 0.f, 0.f, 0.f};   // hl + lh chain
        accA = __builtin_amdgcn_mfma_f32_16x16x32_bf16(a_h0, q_h[0], accA, 0, 0, 0);
        accB = __builtin_amdgcn_mfma_f32_16x16x32_bf16(a_h0, q_l[0], accB, 0, 0, 0);
        accA = __builtin_amdgcn_mfma_f32_16x16x32_bf16(a_h1, q_h[1], accA, 0, 0, 0);
        accB = __builtin_amdgcn_mfma_f32_16x16x32_bf16(a_h1, q_l[1], accB, 0, 0, 0);
        accB = __builtin_amdgcn_mfma_f32_16x16x32_bf16(a_l0, q_h[0], accB, 0, 0, 0);
        accB = __builtin_amdgcn_mfma_f32_16x16x32_bf16(a_l1, q_h[1], accB, 0, 0, 0);
        float sqjv[4] = {sqj.x, sqj.y, sqj.z, sqj.w};
#pragma unroll
        for (int qq = 0; qq < 4; ++qq) {
            float base = sqi + sqjv[qq];
            float d = fmaf(-2.f, accA[qq], fmaf(-2.f, accB[qq], base));
            d = fmaxf(d, 0.f);
            unsigned u = __float_as_uint(d);
            if (u <= thr) {   // stale thr is larger -> conservative-safe
                e[7] = e[6]; e[6] = e[5]; e[5] = e[4]; e[4] = e[3];
                e[3] = e[2]; e[2] = e[1]; e[1] = e[0];
                e[0] = (((ull)u) << 32) | (unsigned)(cc + fg * 4 + qq);
                ++cnt;
            }
        }
        if (__any(cnt >= 5)) {   // drain (cnt <= 8 structurally; empties = ~0ull)
            merge8(k20, e);
#pragma unroll
            for (int j = 0; j < 8; ++j) e[j] = ~0ull;
            cnt = 0;
            // thr = min( max_lanes(k20[4]), min_lanes(k20[19]) )
            unsigned t5  = (unsigned)(k20[4]  >> 32);
            unsigned t20 = (unsigned)(k20[19] >> 32);
            unsigned o;
            o = __shfl_xor(t5, 16);  t5  = (o > t5)  ? o : t5;
            o = __shfl_xor(t5, 32);  t5  = (o > t5)  ? o : t5;
            o = __shfl_xor(t20, 16); t20 = (o < t20) ? o : t20;
            o = __shfl_xor(t20, 32); t20 = (o < t20) ? o : t20;
            thr = (t5 < t20) ? t5 : t20;
        }
    }
    if (__any(cnt >= 1)) {   // final drain
        merge8(k20, e);
    }

    // end-merge: pull groups 1..3's sorted lists into the fg==0 lanes via u64 shuffles
#pragma unroll
    for (int g = 1; g < 4; ++g) {
        for (int p = 0; p < KNN; ++p) {
            ull key = __shfl(k20[p], fr + 16 * g);   // all lanes participate
            bool useful = (lane < 16) && (key < k20[KNN - 1]);
            if (!__any(useful ? 1 : 0)) break;   // source lists sorted -> done
            if (lane < 16) ins20(k20, key);
        }
    }
    if (lane < 16) {
        int grow = b * N_PTS + blk * 64 + w * 16 + lane;
#pragma unroll
        for (int p = 0; p < KNN; ++p)
            part[((size_t)(slice * KNN + p)) * NROWS + grow] = k20[p];
    }
}

// ---------------------------------------------------------- K2: merge slice partials
__global__ void knn_merge(const ull* __restrict__ part, int* __restrict__ knn) {
    int row = blockIdx.x * blockDim.x + threadIdx.x;
    if (row >= NROWS) return;
    ull fin[KNN];
#pragma unroll
    for (int p = 0; p < KNN; ++p) fin[p] = part[(size_t)p * NROWS + row];
    for (int sl = 1; sl < NSLICE; ++sl) {
        for (int p = 0; p < KNN; ++p) {
            ull key = part[(size_t)(sl * KNN + p) * NROWS + row];
            if (key >= fin[KNN - 1]) break;   // slice lists are sorted
            ins20(fin, key);
        }
    }
#pragma unroll
    for (int q = 0; q < KNN; ++q)
        knn[(size_t)q * NROWS + row] = (int)(unsigned)(fin[q] & 0xffffffffu);
}

// ------------------------------------- K4: edge-feature max + MLP1 (128->32) + relu
__global__ void edge_mlp1(const float* __restrict__ x, const int* __restrict__ knn,
                          const float* __restrict__ w1, const float* __restrict__ b1,
                          float* __restrict__ h1) {
    __shared__ float w1t[H1C][132];
    __shared__ float feat[4][128];
    int tid = threadIdx.x;
    int wave = tid >> 6, lane = tid & 63;
    for (int idx = tid; idx < 128 * H1C; idx += 256) {
        int f = idx >> 5, c = idx & 31;
        w1t[c][f] = w1[idx];
    }
    int row = blockIdx.x * 4 + wave;
    int b = row >> 12;
    int n = row & (N_PTS - 1);
    const float* xb = x + (size_t)b * N_PTS * D_DIM;
    float central = xb[(size_t)n * D_DIM + lane];
    float m = -1e30f;
    for (int k = 0; k < KNN; ++k) {
        int j = knn[(size_t)k * NROWS + row];
        float xn = xb[(size_t)j * D_DIM + lane];
        m = fmaxf(m, xn - central);
    }
    feat[wave][lane] = central;
    feat[wave][64 + lane] = m;
    __syncthreads();
    if (lane < H1C) {
        int c = lane;
        float acc = b1[c];
#pragma unroll
        for (int fq = 0; fq < 32; ++fq) {
            float4 fv = *(const float4*)(&feat[wave][fq * 4]);
            float4 wv = *(const float4*)(&w1t[c][fq * 4]);
            acc = fmaf(fv.x, wv.x, acc);
            acc = fmaf(fv.y, wv.y, acc);
            acc = fmaf(fv.z, wv.z, acc);
            acc = fmaf(fv.w, wv.w, acc);
        }
        h1[(size_t)row * H1C + c] = fmaxf(acc, 0.f);
    }
}

// ------------------------------------------------- K5/K7: BN stats (sum, sumsq)
template <int CH>
__global__ void stats_kernel(const float* __restrict__ h, float* __restrict__ sum,
                             float* __restrict__ sumsq) {
    const int RPI = 256 / CH;
    int tid = threadIdx.x;
    int c = tid % CH;
    int r0 = tid / CH;
    float s = 0.f, s2 = 0.f;
    for (int r = blockIdx.x * RPI + r0; r < NROWS; r += gridDim.x * RPI) {
        float v = h[(size_t)r * CH + c];
        s += v;
        s2 = fmaf(v, v, s2);
    }
    __shared__ float ls[256], ls2[256];
    ls[tid] = s; ls2[tid] = s2;
    __syncthreads();
    for (int step = 128; step >= CH; step >>= 1) {
        if (tid < step) { ls[tid] += ls[tid + step]; ls2[tid] += ls2[tid + step]; }
        __syncthreads();
    }
    if (tid < CH) {
        atomicAdd(&sum[tid], ls[tid]);
        atomicAdd(&sumsq[tid], ls2[tid]);
    }
}

// ------------------------------------------------- K6: BN1-coeff (inline) + MLP2 + relu
__global__ void mlp2_kernel(const float* __restrict__ h1, const float* __restrict__ w2,
                            const float* __restrict__ b2, const float* __restrict__ sum1,
                            const float* __restrict__ sumsq1, const float* __restrict__ g1,
                            const float* __restrict__ be1, float* __restrict__ h2) {
    __shared__ float w2s[H1C][H2C];
    __shared__ float hb[4][H1C];
    int tid = threadIdx.x;
    for (int idx = tid; idx < H1C * H2C; idx += 256)
        w2s[idx >> 6][idx & 63] = w2[idx];
    int rw = tid >> 6;
    int c = tid & 63;
    int row = blockIdx.x * 4 + rw;
    if (c < H1C) {
        float mean = sum1[c] * (1.f / NROWS);
        float var = sumsq1[c] * (1.f / NROWS) - mean * mean;
        float aa = g1[c] * rsqrtf(var + BN_EPS);
        float ccf = be1[c] - aa * mean;
        float v = h1[(size_t)row * H1C + c];
        hb[rw][c] = fmaf(aa, v, ccf);
    }
    __syncthreads();
    float acc = b2[c];
#pragma unroll
    for (int f = 0; f < H1C; ++f)
        acc = fmaf(hb[rw][f], w2s[f][c], acc);
    h2[(size_t)row * H2C + c] = fmaxf(acc, 0.f);
}

// ------------------------------------------------- K8: partial max/min over N
__global__ void pool_part(const float* __restrict__ h2, float* __restrict__ pmax,
                          float* __restrict__ pmin) {
    int bb = blockIdx.x >> 6;
    int ch = blockIdx.x & 63;
    int tid = threadIdx.x;
    int rw = tid >> 6, c = tid & 63;
    float mx = -1e30f, mn = 1e30f;
    const float* hbase = h2 + (size_t)bb * N_PTS * H2C;
    for (int n = ch * 64 + rw; n < (ch + 1) * 64; n += 4) {
        float v = hbase[(size_t)n * H2C + c];
        mx = fmaxf(mx, v);
        mn = fminf(mn, v);
    }
    __shared__ float smx[256], smn[256];
    smx[tid] = mx; smn[tid] = mn;
    __syncthreads();
    if (tid < 128) { smx[tid] = fmaxf(smx[tid], smx[tid + 128]); smn[tid] = fminf(smn[tid], smn[tid + 128]); }
    __syncthreads();
    if (tid < 64) {
        pmax[((size_t)bb * 64 + ch) * 64 + tid] = fmaxf(smx[tid], smx[tid + 64]);
        pmin[((size_t)bb * 64 + ch) * 64 + tid] = fminf(smn[tid], smn[tid + 64]);
    }
}

// ------------------------------------------------- K9: final pool + BN2-coeff (inline)
__global__ void pool_final(const float* pmax, const float* pmin,
                           const float* __restrict__ sum2, const float* __restrict__ sumsq2,
                           const float* __restrict__ g2, const float* __restrict__ be2,
                           float* pooled) {
    int bb = blockIdx.x;
    int c = threadIdx.x;
    float M = -1e30f, m = 1e30f;
    for (int ch = 0; ch < 64; ++ch) {
        M = fmaxf(M, pmax[((size_t)bb * 64 + ch) * 64 + c]);
        m = fminf(m, pmin[((size_t)bb * 64 + ch) * 64 + c]);
    }
    float mean = sum2[c] * (1.f / NROWS);
    float var = sumsq2[c] * (1.f / NROWS) - mean * mean;
    float aa = g2[c] * rsqrtf(var + BN_EPS);
    float ccf = be2[c] - aa * mean;
    pooled[bb * 64 + c] = (aa >= 0.f) ? fmaf(aa, M, ccf) : fmaf(aa, m, ccf);
}

// ------------------------------------------------- K10a: head logits (wd read ONCE)
__global__ __launch_bounds__(256) void logits_kernel(const float* __restrict__ pooled,
                                                     const float* __restrict__ wd,
                                                     const float* __restrict__ bd,
                                                     float* __restrict__ lg) {
    __shared__ float pl[8][64];
    int tid = threadIdx.x;
    for (int i = tid; i < 8 * 64; i += 256) ((float*)pl)[i] = pooled[i];
    __syncthreads();
    int col = blockIdx.x * 64 + (tid & 63);
    int bg = tid >> 6;   // handles batches bg and bg+4
    float acc0 = bd[col];
    float acc1 = acc0;
#pragma unroll
    for (int c = 0; c < 64; ++c) {
        float wv = wd[(size_t)c * N_PTS + col];
        acc0 = fmaf(pl[bg][c], wv, acc0);
        acc1 = fmaf(pl[bg + 4][c], wv, acc1);
    }
    lg[(size_t)bg * N_PTS + col] = acc0;
    lg[(size_t)(bg + 4) * N_PTS + col] = acc1;
}

// ------------------------------------------------- K10b: softmax over logits
__global__ __launch_bounds__(1024) void softmax_kernel(const float* __restrict__ lg,
                                                       float* __restrict__ out) {
    int bb = blockIdx.x;
    int tid = threadIdx.x;
    __shared__ float red[1024];
    float logit[4];
#pragma unroll
    for (int q = 0; q < 4; ++q)
        logit[q] = lg[(size_t)bb * N_PTS + tid + q * 1024];
    float mx = fmaxf(fmaxf(logit[0], logit[1]), fmaxf(logit[2], logit[3]));
    red[tid] = mx;
    __syncthreads();
    for (int s = 512; s >= 1; s >>= 1) {
        if (tid < s) red[tid] = fmaxf(red[tid], red[tid + s]);
        __syncthreads();
    }
    float gmax = red[0];
    __syncthreads();
    float e[4];
    float ssum = 0.f;
#pragma unroll
    for (int q = 0; q < 4; ++q) { e[q] = __expf(logit[q] - gmax); ssum += e[q]; }
    red[tid] = ssum;
    __syncthreads();
    for (int s = 512; s >= 1; s >>= 1) {
        if (tid < s) red[tid] += red[tid + s];
        __syncthreads();
    }
    float inv = 1.f / red[0];
#pragma unroll
    for (int q = 0; q < 4; ++q)
        out[(size_t)bb * N_PTS + tid + q * 1024] = e[q] * inv;
}

// -----------------------------------------------------------------------------
extern "C" void kernel_launch(void* const* d_in, const int* in_sizes, int n_in,
                              void* d_out, int out_size, void* d_ws, size_t ws_size,
                              hipStream_t stream) {
    (void)in_sizes; (void)n_in; (void)out_size; (void)ws_size;
    const float* x   = (const float*)d_in[0];
    const float* w1  = (const float*)d_in[1];
    const float* b1  = (const float*)d_in[2];
    const float* g1  = (const float*)d_in[3];
    const float* be1 = (const float*)d_in[4];
    const float* w2  = (const float*)d_in[5];
    const float* b2  = (const float*)d_in[6];
    const float* g2  = (const float*)d_in[7];
    const float* be2 = (const float*)d_in[8];
    const float* wd  = (const float*)d_in[9];
    const float* bd  = (const float*)d_in[10];

    char* ws = (char*)d_ws;
    size_t off = 0;
    auto alloc = [&](size_t bytes) -> void* {
        void* p = ws + off;
        off += (bytes + 255) & ~(size_t)255;
        return p;
    };
    ushort* xh = (ushort*)alloc((size_t)NROWS * D_DIM * 2);
    ushort* xl = (ushort*)alloc((size_t)NROWS * D_DIM * 2);
    float* sq = (float*)alloc((size_t)NROWS * 4);
    ull* part = (ull*)alloc((size_t)NROWS * NSLICE * KNN * 8);   // 10.5 MB
    int* knn = (int*)alloc((size_t)NROWS * KNN * 4);
    float* h1 = (float*)alloc((size_t)NROWS * H1C * 4);
    float* h2 = (float*)alloc((size_t)NROWS * H2C * 4);
    float* stats = (float*)alloc(4096);
    float* pmax = (float*)alloc(8 * 64 * 64 * 4);
    float* pmin = (float*)alloc(8 * 64 * 64 * 4);
    float* pooled = (float*)alloc(8 * 64 * 4);
    float* lg = (float*)alloc((size_t)B_SZ * N_PTS * 4);

    float* sum1 = stats,       *sumsq1 = stats + 32;
    float* sum2 = stats + 128, *sumsq2 = stats + 192;

    hipMemsetAsync(stats, 0, 4096, stream);

    prep_kernel<<<NROWS / 256, 256, 0, stream>>>(x, xh, xl, sq);
    dist_topk<<<dim3(B_SZ * 64, NSLICE), 256, 0, stream>>>(xh, xl, sq, part);
    knn_merge<<<NROWS / 256, 256, 0, stream>>>(part, knn);
    edge_mlp1<<<NROWS / 4, 256, 0, stream>>>(x, knn, w1, b1, h1);
    stats_kernel<H1C><<<256, 256, 0, stream>>>(h1, sum1, sumsq1);
    mlp2_kernel<<<NROWS / 4, 256, 0, stream>>>(h1, w2, b2, sum1, sumsq1, g1, be1, h2);
    stats_kernel<H2C><<<256, 256, 0, stream>>>(h2, sum2, sumsq2);
    pool_part<<<512, 256, 0, stream>>>(h2, pmax, pmin);
    pool_final<<<8, 64, 0, stream>>>(pmax, pmin, sum2, sumsq2, g2, be2, pooled);
    logits_kernel<<<64, 256, 0, stream>>>(pooled, wd, bd, lg);
    softmax_kernel<<<8, 1024, 0, stream>>>(lg, (float*)d_out);
}

// Round 16
// 409.846 us; speedup vs baseline: 1.1079x; 1.1079x over previous
//
#include <hip/hip_runtime.h>
#include <stdint.h>

#define N_PTS 4096
#define B_SZ 8
#define D_DIM 64
#define KNN 20
#define NROWS (B_SZ * N_PTS)   // 32768
#define H1C 32
#define H2C 64
#define BN_EPS 1e-3f
#define NSLICE 2
#define SLICE_C (N_PTS / NSLICE)   // 2048 candidates per block
#define NT (SLICE_C / 64)          // 32 candidate tiles per block

typedef __attribute__((ext_vector_type(8))) short bf16x8;
typedef __attribute__((ext_vector_type(4))) float f32x4;
typedef unsigned long long ull;

__device__ __forceinline__ ushort f2bf(float f) {
    uint32_t u = __float_as_uint(f);
    uint32_t r = (u + 0x7fffu + ((u >> 16) & 1u)) >> 16;
    return (ushort)r;
}
__device__ __forceinline__ float bf2f(ushort h) {
    return __uint_as_float(((uint32_t)h) << 16);
}

// sorted ascending top-20 insert (cold paths: end-merge, knn_merge)
__device__ __forceinline__ void ins20(ull (&k)[KNN], ull cur) {
#pragma unroll
    for (int p = KNN - 1; p >= 1; --p) {
        bool c = cur < k[p - 1];
        ull t = (k[p] < cur) ? k[p] : cur;
        k[p] = c ? k[p - 1] : t;
    }
    k[0] = (k[0] < cur) ? k[0] : cur;
}

// compare-exchange ascending
__device__ __forceinline__ void ce_asc(ull& a, ull& b) {
    bool c = b < a;
    ull lo = c ? b : a;
    ull hi = c ? a : b;
    a = lo;
    b = hi;
}

// Merge batch e[8] (empty slots = ~0ull = +inf; real keys < ~0ull since dist bits
// <= 0x7F7FFFFF) into sorted-asc k[20], keeping the smallest 20. Fixed bitonic
// network, exact via the bitonic split property. (r14, measured best)
__device__ __forceinline__ void merge8(ull (&k)[KNN], ull (&e)[8]) {
    // Batcher odd-even mergesort 8 (ascending), 19 CE
    ce_asc(e[0], e[1]); ce_asc(e[2], e[3]); ce_asc(e[4], e[5]); ce_asc(e[6], e[7]);
    ce_asc(e[0], e[2]); ce_asc(e[1], e[3]); ce_asc(e[4], e[6]); ce_asc(e[5], e[7]);
    ce_asc(e[1], e[2]); ce_asc(e[5], e[6]);
    ce_asc(e[0], e[4]); ce_asc(e[1], e[5]); ce_asc(e[2], e[6]); ce_asc(e[3], e[7]);
    ce_asc(e[2], e[4]); ce_asc(e[3], e[5]);
    ce_asc(e[1], e[2]); ce_asc(e[3], e[4]); ce_asc(e[5], e[6]);
    // split stage: k[8+j] pairs with e[7-j]
    ull u[12];
    u[0] = k[16]; u[1] = k[17]; u[2] = k[18]; u[3] = k[19];
#pragma unroll
    for (int j = 0; j < 8; ++j) {
        ull a = k[8 + j], b = e[7 - j];
        bool c = b < a;
        k[8 + j] = c ? b : a;
        ull hi = c ? a : b;
        if (j < 4) u[8 + j] = hi;
        else       u[j]     = hi;
    }
    // lower 16: bitonic sort
#pragma unroll
    for (int j = 0; j < 8; ++j) ce_asc(k[j], k[j + 8]);
#pragma unroll
    for (int j = 0; j < 4; ++j) { ce_asc(k[j], k[j + 4]); ce_asc(k[8 + j], k[12 + j]); }
#pragma unroll
    for (int j = 0; j < 2; ++j) {
        ce_asc(k[j], k[j + 2]);       ce_asc(k[4 + j], k[6 + j]);
        ce_asc(k[8 + j], k[10 + j]);  ce_asc(k[12 + j], k[14 + j]);
    }
#pragma unroll
    for (int j = 0; j < 16; j += 2) ce_asc(k[j], k[j + 1]);
    // upper 16: extract sorted min-4
#pragma unroll
    for (int j = 0; j < 4; ++j) ce_asc(u[j], u[j + 8]);
#pragma unroll
    for (int j = 0; j < 4; ++j) ce_asc(u[j], u[j + 4]);
    ce_asc(u[0], u[2]); ce_asc(u[1], u[3]);
    ce_asc(u[0], u[1]); ce_asc(u[2], u[3]);
    k[16] = u[0]; k[17] = u[1]; k[18] = u[2]; k[19] = u[3];
}

// ---------------------------------------------------- K0: split fp32 -> bf16 hi/lo + sq
__global__ void prep_kernel(const float* __restrict__ x, ushort* __restrict__ xh,
                            ushort* __restrict__ xl, float* __restrict__ sq) {
    int row = blockIdx.x * blockDim.x + threadIdx.x;
    if (row >= NROWS) return;
    const float4* xr = (const float4*)(x + (size_t)row * D_DIM);
    ushort4* ho = (ushort4*)(xh + (size_t)row * D_DIM);
    ushort4* lo = (ushort4*)(xl + (size_t)row * D_DIM);
    float acc = 0.f;
#pragma unroll
    for (int q = 0; q < 16; ++q) {
        float4 v = xr[q];
        acc = fmaf(v.x, v.x, acc);
        acc = fmaf(v.y, v.y, acc);
        acc = fmaf(v.z, v.z, acc);
        acc = fmaf(v.w, v.w, acc);
        ushort4 h, l;
        h.x = f2bf(v.x); l.x = f2bf(v.x - bf2f(h.x));
        h.y = f2bf(v.y); l.y = f2bf(v.y - bf2f(h.y));
        h.z = f2bf(v.z); l.z = f2bf(v.z - bf2f(h.z));
        h.w = f2bf(v.w); l.w = f2bf(v.w - bf2f(h.w));
        ho[q] = h; lo[q] = l;
    }
    sq[row] = acc;
}

// ---------------------------------------------------- K1: MFMA dist + network-drain topk
// r14 VERBATIM (measured best: 320 µs). Exact u64 keys, 8-deep reg shift buffer, drain
// at __any(cnt>=5) via merge8 bitonic network, dual-bound threshold, XCD-aligned batch
// mapping. NO software pipelining (r15: regressed — compiler schedule is better).
// launch_bounds min-waves MUST stay 4 — 6 forces VGPR cap -> scratch spill (r7: 2.3 GB).
__global__ __launch_bounds__(256, 4) void dist_topk(
    const ushort* __restrict__ xh, const ushort* __restrict__ xl,
    const float* __restrict__ sq, ull* __restrict__ part) {
    int tid = threadIdx.x;
    int lane = tid & 63;
    int w = tid >> 6;
    int b = blockIdx.x & 7;           // batch = XCD (round-robin alignment, r13)
    int blk = blockIdx.x >> 3;        // row-group within batch (0..63)
    int slice = blockIdx.y;
    const ushort* xhb = xh + (size_t)b * N_PTS * D_DIM;
    const ushort* xlb = xl + (size_t)b * N_PTS * D_DIM;
    const float* sqb = sq + (size_t)b * N_PTS;

    int qr0 = blk * 64 + w * 16;          // wave's query-row base (within batch)
    int fr = lane & 15;                   // query row within 16 (C col)
    int fg = lane >> 4;                   // k-group / candidate sub-row group

    // B fragments = query rows, resident all kernel
    bf16x8 q_h[2], q_l[2];
    {
        const ushort* ph = xhb + (size_t)(qr0 + fr) * D_DIM + fg * 8;
        const ushort* pl = xlb + (size_t)(qr0 + fr) * D_DIM + fg * 8;
        q_h[0] = *(const bf16x8*)(ph);
        q_h[1] = *(const bf16x8*)(ph + 32);
        q_l[0] = *(const bf16x8*)(pl);
        q_l[1] = *(const bf16x8*)(pl + 32);
    }
    float sqi = sqb[qr0 + fr];

    ull k20[KNN];
#pragma unroll
    for (int p = 0; p < KNN; ++p) k20[p] = ~0ull;
    ull e[8];
#pragma unroll
    for (int i = 0; i < 8; ++i) e[i] = ~0ull;
    int cnt = 0;
    unsigned thr = 0xFFFFFFFFu;

    int cbase = slice * SLICE_C;
    const ushort* pah = xhb + (size_t)(cbase + fr) * D_DIM + fg * 8;
    const ushort* pal = xlb + (size_t)(cbase + fr) * D_DIM + fg * 8;
    const float* psq = sqb + cbase + fg * 4;

    for (int t = 0; t < NT; ++t) {
        int c0 = cbase + t * 64;
#pragma unroll
        for (int s = 0; s < 4; ++s) {
            int cc = c0 + s * 16;
            bf16x8 a_h0 = *(const bf16x8*)(pah + s * 16 * D_DIM);
            bf16x8 a_h1 = *(const bf16x8*)(pah + s * 16 * D_DIM + 32);
            bf16x8 a_l0 = *(const bf16x8*)(pal + s * 16 * D_DIM);
            bf16x8 a_l1 = *(const bf16x8*)(pal + s * 16 * D_DIM + 32);
            float4 sqj = *(const float4*)(psq + s * 16);
            f32x4 accA = {0.f, 0.f, 0.f, 0.f};   // hh chain
            f32x4 accB = {0.f, 0.f, 0.f, 0.f};   // hl + lh chain
            accA = __builtin_amdgcn_mfma_f32_16x16x32_bf16(a_h0, q_h[0], accA, 0, 0, 0);
            accB = __builtin_amdgcn_mfma_f32_16x16x32_bf16(a_h0, q_l[0], accB, 0, 0, 0);
            accA = __builtin_amdgcn_mfma_f32_16x16x32_bf16(a_h1, q_h[1], accA, 0, 0, 0);
            accB = __builtin_amdgcn_mfma_f32_16x16x32_bf16(a_h1, q_l[1], accB, 0, 0, 0);
            accB = __builtin_amdgcn_mfma_f32_16x16x32_bf16(a_l0, q_h[0], accB, 0, 0, 0);
            accB = __builtin_amdgcn_mfma_f32_16x16x32_bf16(a_l1, q_h[1], accB, 0, 0, 0);
            float sqjv[4] = {sqj.x, sqj.y, sqj.z, sqj.w};
#pragma unroll
            for (int qq = 0; qq < 4; ++qq) {
                float base = sqi + sqjv[qq];
                float d = fmaf(-2.f, accA[qq], fmaf(-2.f, accB[qq], base));
                d = fmaxf(d, 0.f);
                unsigned u = __float_as_uint(d);
                if (u <= thr) {   // stale thr is larger -> conservative-safe
                    e[7] = e[6]; e[6] = e[5]; e[5] = e[4]; e[4] = e[3];
                    e[3] = e[2]; e[2] = e[1]; e[1] = e[0];
                    e[0] = (((ull)u) << 32) | (unsigned)(cc + fg * 4 + qq);
                    ++cnt;
                }
            }
            if (__any(cnt >= 5)) {   // drain (cnt <= 8 structurally; empties = ~0ull)
                merge8(k20, e);
#pragma unroll
                for (int i = 0; i < 8; ++i) e[i] = ~0ull;
                cnt = 0;
                // thr = min( max_lanes(k20[4]), min_lanes(k20[19]) )
                unsigned t5  = (unsigned)(k20[4]  >> 32);
                unsigned t20 = (unsigned)(k20[19] >> 32);
                unsigned o;
                o = __shfl_xor(t5, 16);  t5  = (o > t5)  ? o : t5;
                o = __shfl_xor(t5, 32);  t5  = (o > t5)  ? o : t5;
                o = __shfl_xor(t20, 16); t20 = (o < t20) ? o : t20;
                o = __shfl_xor(t20, 32); t20 = (o < t20) ? o : t20;
                thr = (t5 < t20) ? t5 : t20;
            }
        }
        pah += 64 * D_DIM;
        pal += 64 * D_DIM;
        psq += 64;
    }
    if (__any(cnt >= 1)) {   // final drain (cnt <= 4; empties = ~0ull)
        merge8(k20, e);
    }

    // end-merge: pull groups 1..3's sorted lists into the fg==0 lanes via u64 shuffles
#pragma unroll
    for (int g = 1; g < 4; ++g) {
        for (int p = 0; p < KNN; ++p) {
            ull key = __shfl(k20[p], fr + 16 * g);   // all lanes participate
            bool useful = (lane < 16) && (key < k20[KNN - 1]);
            if (!__any(useful ? 1 : 0)) break;   // source lists sorted -> done
            if (lane < 16) ins20(k20, key);
        }
    }
    if (lane < 16) {
        int grow = b * N_PTS + blk * 64 + w * 16 + lane;
#pragma unroll
        for (int p = 0; p < KNN; ++p)
            part[((size_t)(slice * KNN + p)) * NROWS + grow] = k20[p];
    }
}

// ---------------------------------------------------------- K2: merge slice partials
__global__ void knn_merge(const ull* __restrict__ part, int* __restrict__ knn) {
    int row = blockIdx.x * blockDim.x + threadIdx.x;
    if (row >= NROWS) return;
    ull fin[KNN];
#pragma unroll
    for (int p = 0; p < KNN; ++p) fin[p] = part[(size_t)p * NROWS + row];
    for (int sl = 1; sl < NSLICE; ++sl) {
        for (int p = 0; p < KNN; ++p) {
            ull key = part[(size_t)(sl * KNN + p) * NROWS + row];
            if (key >= fin[KNN - 1]) break;   // slice lists are sorted
            ins20(fin, key);
        }
    }
#pragma unroll
    for (int q = 0; q < KNN; ++q)
        knn[(size_t)q * NROWS + row] = (int)(unsigned)(fin[q] & 0xffffffffu);
}

// ------------------------------------- K4: edge-feature max + MLP1 (128->32) + relu
__global__ void edge_mlp1(const float* __restrict__ x, const int* __restrict__ knn,
                          const float* __restrict__ w1, const float* __restrict__ b1,
                          float* __restrict__ h1) {
    __shared__ float w1t[H1C][132];
    __shared__ float feat[4][128];
    int tid = threadIdx.x;
    int wave = tid >> 6, lane = tid & 63;
    for (int idx = tid; idx < 128 * H1C; idx += 256) {
        int f = idx >> 5, c = idx & 31;
        w1t[c][f] = w1[idx];
    }
    int row = blockIdx.x * 4 + wave;
    int b = row >> 12;
    int n = row & (N_PTS - 1);
    const float* xb = x + (size_t)b * N_PTS * D_DIM;
    float central = xb[(size_t)n * D_DIM + lane];
    float m = -1e30f;
    for (int k = 0; k < KNN; ++k) {
        int j = knn[(size_t)k * NROWS + row];
        float xn = xb[(size_t)j * D_DIM + lane];
        m = fmaxf(m, xn - central);
    }
    feat[wave][lane] = central;
    feat[wave][64 + lane] = m;
    __syncthreads();
    if (lane < H1C) {
        int c = lane;
        float acc = b1[c];
#pragma unroll
        for (int fq = 0; fq < 32; ++fq) {
            float4 fv = *(const float4*)(&feat[wave][fq * 4]);
            float4 wv = *(const float4*)(&w1t[c][fq * 4]);
            acc = fmaf(fv.x, wv.x, acc);
            acc = fmaf(fv.y, wv.y, acc);
            acc = fmaf(fv.z, wv.z, acc);
            acc = fmaf(fv.w, wv.w, acc);
        }
        h1[(size_t)row * H1C + c] = fmaxf(acc, 0.f);
    }
}

// ------------------------------------------------- K5/K7: BN stats (sum, sumsq)
template <int CH>
__global__ void stats_kernel(const float* __restrict__ h, float* __restrict__ sum,
                             float* __restrict__ sumsq) {
    const int RPI = 256 / CH;
    int tid = threadIdx.x;
    int c = tid % CH;
    int r0 = tid / CH;
    float s = 0.f, s2 = 0.f;
    for (int r = blockIdx.x * RPI + r0; r < NROWS; r += gridDim.x * RPI) {
        float v = h[(size_t)r * CH + c];
        s += v;
        s2 = fmaf(v, v, s2);
    }
    __shared__ float ls[256], ls2[256];
    ls[tid] = s; ls2[tid] = s2;
    __syncthreads();
    for (int step = 128; step >= CH; step >>= 1) {
        if (tid < step) { ls[tid] += ls[tid + step]; ls2[tid] += ls2[tid + step]; }
        __syncthreads();
    }
    if (tid < CH) {
        atomicAdd(&sum[tid], ls[tid]);
        atomicAdd(&sumsq[tid], ls2[tid]);
    }
}

// ------------------------------------------------- K6: BN1-coeff (inline) + MLP2 + relu
__global__ void mlp2_kernel(const float* __restrict__ h1, const float* __restrict__ w2,
                            const float* __restrict__ b2, const float* __restrict__ sum1,
                            const float* __restrict__ sumsq1, const float* __restrict__ g1,
                            const float* __restrict__ be1, float* __restrict__ h2) {
    __shared__ float w2s[H1C][H2C];
    __shared__ float hb[4][H1C];
    int tid = threadIdx.x;
    for (int idx = tid; idx < H1C * H2C; idx += 256)
        w2s[idx >> 6][idx & 63] = w2[idx];
    int rw = tid >> 6;
    int c = tid & 63;
    int row = blockIdx.x * 4 + rw;
    if (c < H1C) {
        float mean = sum1[c] * (1.f / NROWS);
        float var = sumsq1[c] * (1.f / NROWS) - mean * mean;
        float aa = g1[c] * rsqrtf(var + BN_EPS);
        float ccf = be1[c] - aa * mean;
        float v = h1[(size_t)row * H1C + c];
        hb[rw][c] = fmaf(aa, v, ccf);
    }
    __syncthreads();
    float acc = b2[c];
#pragma unroll
    for (int f = 0; f < H1C; ++f)
        acc = fmaf(hb[rw][f], w2s[f][c], acc);
    h2[(size_t)row * H2C + c] = fmaxf(acc, 0.f);
}

// ------------------------------------------------- K8: partial max/min over N
__global__ void pool_part(const float* __restrict__ h2, float* __restrict__ pmax,
                          float* __restrict__ pmin) {
    int bb = blockIdx.x >> 6;
    int ch = blockIdx.x & 63;
    int tid = threadIdx.x;
    int rw = tid >> 6, c = tid & 63;
    float mx = -1e30f, mn = 1e30f;
    const float* hbase = h2 + (size_t)bb * N_PTS * H2C;
    for (int n = ch * 64 + rw; n < (ch + 1) * 64; n += 4) {
        float v = hbase[(size_t)n * H2C + c];
        mx = fmaxf(mx, v);
        mn = fminf(mn, v);
    }
    __shared__ float smx[256], smn[256];
    smx[tid] = mx; smn[tid] = mn;
    __syncthreads();
    if (tid < 128) { smx[tid] = fmaxf(smx[tid], smx[tid + 128]); smn[tid] = fminf(smn[tid], smn[tid + 128]); }
    __syncthreads();
    if (tid < 64) {
        pmax[((size_t)bb * 64 + ch) * 64 + tid] = fmaxf(smx[tid], smx[tid + 64]);
        pmin[((size_t)bb * 64 + ch) * 64 + tid] = fminf(smn[tid], smn[tid + 64]);
    }
}

// ------------------------------------------------- K9: final pool + BN2-coeff (inline)
__global__ void pool_final(const float* pmax, const float* pmin,
                           const float* __restrict__ sum2, const float* __restrict__ sumsq2,
                           const float* __restrict__ g2, const float* __restrict__ be2,
                           float* pooled) {
    int bb = blockIdx.x;
    int c = threadIdx.x;
    float M = -1e30f, m = 1e30f;
    for (int ch = 0; ch < 64; ++ch) {
        M = fmaxf(M, pmax[((size_t)bb * 64 + ch) * 64 + c]);
        m = fminf(m, pmin[((size_t)bb * 64 + ch) * 64 + c]);
    }
    float mean = sum2[c] * (1.f / NROWS);
    float var = sumsq2[c] * (1.f / NROWS) - mean * mean;
    float aa = g2[c] * rsqrtf(var + BN_EPS);
    float ccf = be2[c] - aa * mean;
    pooled[bb * 64 + c] = (aa >= 0.f) ? fmaf(aa, M, ccf) : fmaf(aa, m, ccf);
}

// ------------------------------------------------- K10a: head logits (wd read ONCE)
__global__ __launch_bounds__(256) void logits_kernel(const float* __restrict__ pooled,
                                                     const float* __restrict__ wd,
                                                     const float* __restrict__ bd,
                                                     float* __restrict__ lg) {
    __shared__ float pl[8][64];
    int tid = threadIdx.x;
    for (int i = tid; i < 8 * 64; i += 256) ((float*)pl)[i] = pooled[i];
    __syncthreads();
    int col = blockIdx.x * 64 + (tid & 63);
    int bg = tid >> 6;   // handles batches bg and bg+4
    float acc0 = bd[col];
    float acc1 = acc0;
#pragma unroll
    for (int c = 0; c < 64; ++c) {
        float wv = wd[(size_t)c * N_PTS + col];
        acc0 = fmaf(pl[bg][c], wv, acc0);
        acc1 = fmaf(pl[bg + 4][c], wv, acc1);
    }
    lg[(size_t)bg * N_PTS + col] = acc0;
    lg[(size_t)(bg + 4) * N_PTS + col] = acc1;
}

// ------------------------------------------------- K10b: softmax over logits
__global__ __launch_bounds__(1024) void softmax_kernel(const float* __restrict__ lg,
                                                       float* __restrict__ out) {
    int bb = blockIdx.x;
    int tid = threadIdx.x;
    __shared__ float red[1024];
    float logit[4];
#pragma unroll
    for (int q = 0; q < 4; ++q)
        logit[q] = lg[(size_t)bb * N_PTS + tid + q * 1024];
    float mx = fmaxf(fmaxf(logit[0], logit[1]), fmaxf(logit[2], logit[3]));
    red[tid] = mx;
    __syncthreads();
    for (int s = 512; s >= 1; s >>= 1) {
        if (tid < s) red[tid] = fmaxf(red[tid], red[tid + s]);
        __syncthreads();
    }
    float gmax = red[0];
    __syncthreads();
    float e[4];
    float ssum = 0.f;
#pragma unroll
    for (int q = 0; q < 4; ++q) { e[q] = __expf(logit[q] - gmax); ssum += e[q]; }
    red[tid] = ssum;
    __syncthreads();
    for (int s = 512; s >= 1; s >>= 1) {
        if (tid < s) red[tid] += red[tid + s];
        __syncthreads();
    }
    float inv = 1.f / red[0];
#pragma unroll
    for (int q = 0; q < 4; ++q)
        out[(size_t)bb * N_PTS + tid + q * 1024] = e[q] * inv;
}

// -----------------------------------------------------------------------------
extern "C" void kernel_launch(void* const* d_in, const int* in_sizes, int n_in,
                              void* d_out, int out_size, void* d_ws, size_t ws_size,
                              hipStream_t stream) {
    (void)in_sizes; (void)n_in; (void)out_size; (void)ws_size;
    const float* x   = (const float*)d_in[0];
    const float* w1  = (const float*)d_in[1];
    const float* b1  = (const float*)d_in[2];
    const float* g1  = (const float*)d_in[3];
    const float* be1 = (const float*)d_in[4];
    const float* w2  = (const float*)d_in[5];
    const float* b2  = (const float*)d_in[6];
    const float* g2  = (const float*)d_in[7];
    const float* be2 = (const float*)d_in[8];
    const float* wd  = (const float*)d_in[9];
    const float* bd  = (const float*)d_in[10];

    char* ws = (char*)d_ws;
    size_t off = 0;
    auto alloc = [&](size_t bytes) -> void* {
        void* p = ws + off;
        off += (bytes + 255) & ~(size_t)255;
        return p;
    };
    ushort* xh = (ushort*)alloc((size_t)NROWS * D_DIM * 2);
    ushort* xl = (ushort*)alloc((size_t)NROWS * D_DIM * 2);
    float* sq = (float*)alloc((size_t)NROWS * 4);
    ull* part = (ull*)alloc((size_t)NROWS * NSLICE * KNN * 8);   // 10.5 MB
    int* knn = (int*)alloc((size_t)NROWS * KNN * 4);
    float* h1 = (float*)alloc((size_t)NROWS * H1C * 4);
    float* h2 = (float*)alloc((size_t)NROWS * H2C * 4);
    float* stats = (float*)alloc(4096);
    float* pmax = (float*)alloc(8 * 64 * 64 * 4);
    float* pmin = (float*)alloc(8 * 64 * 64 * 4);
    float* pooled = (float*)alloc(8 * 64 * 4);
    float* lg = (float*)alloc((size_t)B_SZ * N_PTS * 4);

    float* sum1 = stats,       *sumsq1 = stats + 32;
    float* sum2 = stats + 128, *sumsq2 = stats + 192;

    hipMemsetAsync(stats, 0, 4096, stream);

    prep_kernel<<<NROWS / 256, 256, 0, stream>>>(x, xh, xl, sq);
    dist_topk<<<dim3(B_SZ * 64, NSLICE), 256, 0, stream>>>(xh, xl, sq, part);
    knn_merge<<<NROWS / 256, 256, 0, stream>>>(part, knn);
    edge_mlp1<<<NROWS / 4, 256, 0, stream>>>(x, knn, w1, b1, h1);
    stats_kernel<H1C><<<256, 256, 0, stream>>>(h1, sum1, sumsq1);
    mlp2_kernel<<<NROWS / 4, 256, 0, stream>>>(h1, w2, b2, sum1, sumsq1, g1, be1, h2);
    stats_kernel<H2C><<<256, 256, 0, stream>>>(h2, sum2, sumsq2);
    pool_part<<<512, 256, 0, stream>>>(h2, pmax, pmin);
    pool_final<<<8, 64, 0, stream>>>(pmax, pmin, sum2, sumsq2, g2, be2, pooled);
    logits_kernel<<<64, 256, 0, stream>>>(pooled, wd, bd, lg);
    softmax_kernel<<<8, 1024, 0, stream>>>(lg, (float*)d_out);
}